// Round 2
// 158.731 us; speedup vs baseline: 1.0081x; 1.0081x over previous
//
#include <hip/hip_runtime.h>
#include <hip/hip_bf16.h>

typedef float f32x4 __attribute__((ext_vector_type(4)));
typedef __bf16 bf16x8 __attribute__((ext_vector_type(8)));
typedef _Float16 f16x2 __attribute__((ext_vector_type(2)));
typedef _Float16 f16x4 __attribute__((ext_vector_type(4)));
typedef _Float16 f16x8 __attribute__((ext_vector_type(8)));
typedef unsigned short u16;

// fp32 -> bf16 RNE (host-independent scalar path, used only in cvt_w)
__device__ inline u16 f2bf(float f) {
    unsigned int u = __float_as_uint(f);
    return (u16)((u + 0x7fffu + ((u >> 16) & 1u)) >> 16);
}

// fp32x2 -> fp16x2 RTZ via v_cvt_pkrtz_f16_f32; union bridges __fp16/_Float16.
__device__ inline f16x2 pkrtz(float a, float b) {
    union { __fp16 h __attribute__((ext_vector_type(2))); f16x2 f; } r;
    r.h = __builtin_amdgcn_cvt_pkrtz(a, b);
    return r.f;
}

// B' = [W1_top | W1_bot] as 128(K) x 128(N), bf16, MFMA fragment order. (unchanged)
__global__ __launch_bounds__(256) void cvt_w_kernel(const float* __restrict__ W1,
                                                    u16* __restrict__ wf) {
    int i = blockIdx.x * 256 + threadIdx.x;
    if (i >= 128 * 128) return;
    int j = i & 7, fl = i >> 3;
    int lane = fl & 63, kbt = fl >> 6;
    int kb = kbt >> 3, t = kbt & 7;
    int k = kb * 32 + ((lane >> 4) & 3) * 8 + j;
    int n = t * 16 + (lane & 15);
    int krow = k + ((n >= 64) ? 128 : 0);
    wf[i] = f2bf(W1[krow * 64 + (n & 63)]);
}

// Packed f32->bf16 convert: 4 instructions instead of ~32 scalar bit-twiddles.
__device__ inline bf16x8 pack8(const float4 a, const float4 b) {
    union { unsigned int w[4]; bf16x8 v; } r;
    asm("v_cvt_pk_bf16_f32 %0, %1, %2" : "=v"(r.w[0]) : "v"(a.x), "v"(a.y));
    asm("v_cvt_pk_bf16_f32 %0, %1, %2" : "=v"(r.w[1]) : "v"(a.z), "v"(a.w));
    asm("v_cvt_pk_bf16_f32 %0, %1, %2" : "=v"(r.w[2]) : "v"(b.x), "v"(b.y));
    asm("v_cvt_pk_bf16_f32 %0, %1, %2" : "=v"(r.w[3]) : "v"(b.z), "v"(b.w));
    return r.v;
}

// Dense GEMM: uv[M][128] = emb[M][128] @ B' (+b1 on the u-half), fp16 out.
// uv row layout is PERMUTED per 64-dim half: dim c stored at position
// p = (c&15)*4 + ((c>>4)&3) within its half. This makes each lane's 4
// t-values contiguous -> 8B dwordx2 stores instead of 64x 2B scalar stores.
__global__ __launch_bounds__(256) void uv_gemm_kernel(
    const float* __restrict__ emb, const u16* __restrict__ wf,
    const float* __restrict__ b1, _Float16* __restrict__ uv, int M) {
    __shared__ __align__(16) u16 bsh[32 * 64 * 8];  // 32 KB, frag order

    const int tid = threadIdx.x;
    const int w = tid >> 6, lane = tid & 63, quad = lane >> 4, l15 = lane & 15;
    {
        const uint4* s = (const uint4*)wf;
        uint4* d = (uint4*)bsh;
#pragma unroll
        for (int i = 0; i < 8; ++i) d[tid + i * 256] = s[tid + i * 256];
    }
    __syncthreads();

    const int rb = blockIdx.x * 128 + w * 32;

    bf16x8 a[2][4];
#pragma unroll
    for (int m = 0; m < 2; ++m) {
        int row = rb + m * 16 + l15;
        if (row >= M) row = M - 1;
        const float* p = emb + (long)row * 128 + quad * 8;
#pragma unroll
        for (int kb = 0; kb < 4; ++kb) {
            float4 x = ((const float4*)(p + kb * 32))[0];
            float4 y = ((const float4*)(p + kb * 32))[1];
            a[m][kb] = pack8(x, y);
        }
    }

    f32x4 acc[2][8];
#pragma unroll
    for (int m = 0; m < 2; ++m)
#pragma unroll
        for (int t = 0; t < 8; ++t)
#pragma unroll
            for (int r = 0; r < 4; ++r) acc[m][t][r] = 0.0f;

#pragma unroll
    for (int kb = 0; kb < 4; ++kb)
#pragma unroll
        for (int t = 0; t < 8; ++t) {
            bf16x8 bf = *(const bf16x8*)(bsh + ((kb * 8 + t) * 64 + lane) * 8);
#pragma unroll
            for (int m = 0; m < 2; ++m)
                acc[m][t] = __builtin_amdgcn_mfma_f32_16x16x32_bf16(a[m][kb], bf,
                                                                    acc[m][t], 0, 0, 0);
        }

    // b1 fold: u-half col c = t*16 + l15 (t<4) -> bias b1[c]; v-half gets none.
    float b1c[4];
#pragma unroll
    for (int t = 0; t < 4; ++t) b1c[t] = b1[t * 16 + l15];

#pragma unroll
    for (int m = 0; m < 2; ++m)
#pragma unroll
        for (int r = 0; r < 4; ++r) {
            int node = rb + m * 16 + quad * 4 + r;
            if (node >= M) continue;
            f16x2 u0 = pkrtz(acc[m][0][r] + b1c[0], acc[m][1][r] + b1c[1]);
            f16x2 u1 = pkrtz(acc[m][2][r] + b1c[2], acc[m][3][r] + b1c[3]);
            f16x2 v0 = pkrtz(acc[m][4][r], acc[m][5][r]);
            f16x2 v1 = pkrtz(acc[m][6][r], acc[m][7][r]);
            f16x4 su, sv;
            su[0] = u0[0]; su[1] = u0[1]; su[2] = u1[0]; su[3] = u1[1];
            sv[0] = v0[0]; sv[1] = v0[1]; sv[2] = v1[0]; sv[3] = v1[1];
            _Float16* p = uv + (long)node * 128 + l15 * 4;
            *(f16x4*)p = su;          // u-half, positions l15*4 + t
            *(f16x4*)(p + 64) = sv;   // v-half, same permutation
        }
}

__device__ inline f16x2 relu2(f16x2 x) {
    f16x2 r;
    r[0] = (x[0] > (_Float16)0.f) ? x[0] : (_Float16)0.f;
    r[1] = (x[1] > (_Float16)0.f) ? x[1] : (_Float16)0.f;
    return r;
}

__device__ inline float dot2(f16x2 h, f16x2 w, float s) {
#if __has_builtin(__builtin_amdgcn_fdot2)
    return __builtin_amdgcn_fdot2(h, w, s, false);
#else
    return s + (float)h[0] * (float)w[0] + (float)h[1] * (float)w[1];
#endif
}

// Per-edge: score = relu(u'[src] + v[tgt]) . W2 + b2   (u' has b1 folded in).
// 4 lanes per edge; lane q reads f16 positions [q*16, q*16+16) of each half
// (same bytes/lines as before -> identical gather traffic). Position p maps to
// dim d = ((s&3)<<4) + 4q + (s>>2), s = p - q*16; w2 is indexed accordingly.
__global__ __launch_bounds__(256, 8) void edge_score_kernel(
    const _Float16* __restrict__ uv, const int* __restrict__ idx,
    const float* __restrict__ w2, const float* __restrict__ b2,
    float* __restrict__ out, int E, int nT) {
    const int tid = threadIdx.x, w = tid >> 6, lane = tid & 63;
    const int e4 = lane >> 2, q = lane & 3;

    f16x2 w2h[8];
#pragma unroll
    for (int i = 0; i < 8; ++i) {
        int s0 = 2 * i, s1 = 2 * i + 1;
        int d0 = ((s0 & 3) << 4) + (q << 2) + (s0 >> 2);
        int d1 = ((s1 & 3) << 4) + (q << 2) + (s1 >> 2);
        w2h[i][0] = (_Float16)w2[d0];
        w2h[i][1] = (_Float16)w2[d1];
    }
    const float b2v = b2[0];

    const int gw = blockIdx.x * 4 + w, stride = gridDim.x * 4;
    const int step = stride * 2;

    auto ldidx = [&](int tile, int& s, int& t) {
        int e = tile * 16 + e4;
        if (e >= E) e = E - 1;
        s = __builtin_nontemporal_load(idx + e);
        t = __builtin_nontemporal_load(idx + E + e);
    };

    union F8 { f16x8 v; f16x2 p[4]; };

    auto score16 = [&](int src, int tgt) -> float {
        const _Float16* up = uv + (long)src * 128 + q * 16;
        const _Float16* vp = uv + (long)tgt * 128 + 64 + q * 16;
        F8 U0, U1, V0, V1;
        U0.v = *(const f16x8*)up;
        U1.v = *(const f16x8*)(up + 8);
        V0.v = *(const f16x8*)vp;
        V1.v = *(const f16x8*)(vp + 8);
        float s = 0.f;
#pragma unroll
        for (int i = 0; i < 4; ++i) {
            f16x2 h = relu2(U0.p[i] + V0.p[i]);
            s = dot2(h, w2h[i], s);
        }
#pragma unroll
        for (int i = 0; i < 4; ++i) {
            f16x2 h = relu2(U1.p[i] + V1.p[i]);
            s = dot2(h, w2h[4 + i], s);
        }
        return s;
    };

    int sA, tA, sB, tB;
    {
        int t0 = (gw < nT) ? gw : 0;
        int t1 = (gw + stride < nT) ? (gw + stride) : t0;
        ldidx(t0, sA, tA);
        ldidx(t1, sB, tB);
    }

    for (int tile = gw; tile < nT; tile += step) {
        const int tileB = tile + stride;

        // prefetch next pair's indices
        int n0 = tile + step, n1 = tile + step + stride;
        int sA2, tA2, sB2, tB2;
        ldidx(n0 < nT ? n0 : tile, sA2, tA2);
        ldidx(n1 < nT ? n1 : tile, sB2, tB2);

        float sa = score16(sA, tA);
        float sb = score16(sB, tB);

        sa += __shfl_xor(sa, 1, 64);
        sa += __shfl_xor(sa, 2, 64);
        sb += __shfl_xor(sb, 1, 64);
        sb += __shfl_xor(sb, 2, 64);

        if (q == 0) {
            int ea = tile * 16 + e4;
            if (ea < E) __builtin_nontemporal_store(sa + b2v, out + ea);
            if (tileB < nT) {
                int eb = tileB * 16 + e4;
                if (eb < E) __builtin_nontemporal_store(sb + b2v, out + eb);
            }
        }
        sA = sA2; tA = tA2; sB = sB2; tB = tB2;
    }
}

extern "C" void kernel_launch(void* const* d_in, const int* in_sizes, int n_in,
                              void* d_out, int out_size, void* d_ws, size_t ws_size,
                              hipStream_t stream) {
    const float* emb_f = (const float*)d_in[0];
    const int*   idx   = (const int*)d_in[1];
    const float* W1    = (const float*)d_in[2];
    const float* b1    = (const float*)d_in[3];
    const float* W2    = (const float*)d_in[4];
    const float* b2    = (const float*)d_in[5];
    float* out = (float*)d_out;

    const int embN = in_sizes[0];      // N_NODES * 128
    const int M    = embN / 128;       // N_NODES
    const int E    = in_sizes[1] / 2;

    _Float16* uv = (_Float16*)d_ws;    // [M][128] fp16 = 25.6 MB (permuted halves)
    u16* wf = (u16*)(uv + (long)M * 128);  // 32 KB fragment-ordered B'

    cvt_w_kernel<<<64, 256, 0, stream>>>(W1, wf);
    uv_gemm_kernel<<<(M + 127) / 128, 256, 0, stream>>>(emb_f, wf, b1, uv, M);

    int nT = (E + 15) / 16;
    edge_score_kernel<<<2048, 256, 0, stream>>>(uv, idx, W2, b2, out, E, nT);
}